// Round 8
// baseline (160.678 us; speedup 1.0000x reference)
//
#include <hip/hip_runtime.h>

#define D_MODEL 1024
#define L_SEQ   2048
#define N_BATCH 8
#define N_TOK   (N_BATCH * L_SEQ)   // 16384
#define N_REGS  8
#define D_REG   32
#define N_CHUNK 64
#define CHUNK   32
#define LN_EPS  1e-5f

// LDS geometry for k_lnproj4
#define KC      32                  // k-chunk size
#define XSTR    65                  // padded token stride (odd -> conflict-free)
#define XQ      (KC * XSTR)         // dwords per (buffer, quarter) = 2080
#define SSTR    57                  // epilogue tile stride (57%32=25, gcd=1)

__device__ __forceinline__ float wred(float v) {
    #pragma unroll
    for (int off = 32; off > 0; off >>= 1) v += __shfl_xor(v, off, 64);
    return v;
}

__device__ __forceinline__ float sigmoidf(float z) {
    return 1.f / (1.f + expf(-z));
}

// ---------------------------------------------------------------------------
// Prep: fold ln_w into all 49 projection rows, pack as Wpp[g][k][16] with
// features f = g*13+i (i<13; f>=49 zero pads); c1[f] = sum_k W[f,k]*ln_w[k],
// c2[f] = sum_k W[f,k]*ln_b[k] + bias[f].
// Feature order: 0..7 = Wrq, 8..15 = Wwq, 16 = Wwg, 17..48 = Wwv.
// ---------------------------------------------------------------------------
__global__ __launch_bounds__(256) void k_prep(
    const float* __restrict__ ln_w, const float* __restrict__ ln_b,
    const float* __restrict__ Wrq,  const float* __restrict__ brq,
    const float* __restrict__ Wwq,  const float* __restrict__ bwq,
    const float* __restrict__ Wwv,  const float* __restrict__ bwv,
    const float* __restrict__ Wwg,  const float* __restrict__ bwg,
    float* __restrict__ Wpp, float* __restrict__ c1, float* __restrict__ c2)
{
    const int f = blockIdx.x;            // 0..51
    const int g = f / 13, i = f % 13;

    const float* wrow = nullptr; float bias = 0.f;
    if (f < 8)        { wrow = Wrq + f * D_MODEL;        bias = brq[f]; }
    else if (f < 16)  { wrow = Wwq + (f - 8) * D_MODEL;  bias = bwq[f - 8]; }
    else if (f == 16) { wrow = Wwg;                      bias = bwg[0]; }
    else if (f < 49)  { wrow = Wwv + (f - 17) * D_MODEL; bias = bwv[f - 17]; }

    float p1 = 0.f, p2 = 0.f;
    #pragma unroll
    for (int j = 0; j < 4; ++j) {
        const int k = j * 256 + threadIdx.x;
        float w  = wrow ? wrow[k] : 0.f;
        float wg = w * ln_w[k];
        Wpp[((size_t)(g * D_MODEL + k)) * 16 + i] = wg;
        p1 += wg;
        p2 = fmaf(w, ln_b[k], p2);
    }
    p1 = wred(p1); p2 = wred(p2);

    __shared__ float r1[4], r2[4];
    const int l = threadIdx.x & 63, w = threadIdx.x >> 6;
    if (l == 0) { r1[w] = p1; r2[w] = p2; }
    __syncthreads();
    if (threadIdx.x == 0) {
        c1[f] = r1[0] + r1[1] + r1[2] + r1[3];
        c2[f] = r2[0] + r2[1] + r2[2] + r2[3] + bias;
    }
}

// ---------------------------------------------------------------------------
// Inner projection loop over one 32-k LDS chunk. STATS: 0=none, 1=sum, 2=ss.
// Weights come in via the VECTOR path (wr0 carries a laundered VGPR zero so
// the compiler cannot prove uniformity and emits global_load_dwordx4 with
// deep vmcnt pipelining instead of 2-deep s_loads).
// ---------------------------------------------------------------------------
template<int STATS>
__device__ __forceinline__ void proj_chunk(
    const float* __restrict__ lx,      // LDS base: + k*XSTR + lane
    const float4* __restrict__ wr0,    // Wpp record base for this chunk
    int lane, float acc[13], float& st)
{
    #pragma unroll 8
    for (int k = 0; k < KC; ++k) {
        const float xs = lx[k * XSTR + lane];
        const float4* wr = wr0 + (k << 2);
        float4 wa = wr[0], wb = wr[1], wc = wr[2];
        float  wd = reinterpret_cast<const float*>(wr)[12];
        acc[0]  = fmaf(xs, wa.x, acc[0]);
        acc[1]  = fmaf(xs, wa.y, acc[1]);
        acc[2]  = fmaf(xs, wa.z, acc[2]);
        acc[3]  = fmaf(xs, wa.w, acc[3]);
        acc[4]  = fmaf(xs, wb.x, acc[4]);
        acc[5]  = fmaf(xs, wb.y, acc[5]);
        acc[6]  = fmaf(xs, wb.z, acc[6]);
        acc[7]  = fmaf(xs, wb.w, acc[7]);
        acc[8]  = fmaf(xs, wc.x, acc[8]);
        acc[9]  = fmaf(xs, wc.y, acc[9]);
        acc[10] = fmaf(xs, wc.z, acc[10]);
        acc[11] = fmaf(xs, wc.w, acc[11]);
        acc[12] = fmaf(xs, wd,   acc[12]);
        if (STATS == 1) st += xs;
        if (STATS == 2) st = fmaf(xs, xs, st);
    }
}

// ---------------------------------------------------------------------------
// Kernel A v4: LDS-transpose-staged x + vector-path weights.
// Block = 1024 thr = 16 waves (4 feature-groups g x 4 K-quarters kh),
// 64 tokens per block, lane = token. Dynamic LDS: 2*4*XQ + 64*SSTR dwords.
// ---------------------------------------------------------------------------
__global__ __launch_bounds__(1024) void k_lnproj4(
    const float* __restrict__ x,
    const float* __restrict__ Wpp,
    const float* __restrict__ c1, const float* __restrict__ c2,
    float* __restrict__ rw_o, float* __restrict__ us_o, float* __restrict__ wv_o)
{
    extern __shared__ float lds[];
    float* Sb = lds + 2 * 4 * XQ;       // [64][SSTR]

    const int tid  = threadIdx.x;
    const int lane = tid & 63;
    const int wv   = tid >> 6;          // 0..15
    const int g    = wv & 3;            // feature group
    const int kh   = wv >> 2;           // K quarter
    const int tok0 = blockIdx.x * 64;

    const int gs  = __builtin_amdgcn_readfirstlane(g);
    const int khs = __builtin_amdgcn_readfirstlane(kh);

    // laundered zero: lives in a VGPR, defeats uniformity analysis so weight
    // loads take the vector-memory path (deep vmcnt pipelining, L1-cached).
    int lz;
    asm volatile("v_mov_b32 %0, 0" : "=v"(lz));

    // staging ids within the 256-thread quarter-group
    const int tq  = tid & 255;
    const int row = tq >> 3;            // 0..31 (token), +32 on pass 1
    const int c4  = tq & 7;             // float4 column (k_local = c4*4)

    const float4* x4 = reinterpret_cast<const float4*>(x);

    float4 xg[2];
    float acc[13];
    #pragma unroll
    for (int i = 0; i < 13; ++i) acc[i] = 0.f;
    float st = 0.f;

    const size_t gbase = (size_t)(tok0 + row) * 256 + khs * 64 + c4;

    // ---- prologue: stage chunk 0 ------------------------------------------
    {
        xg[0] = x4[gbase];
        xg[1] = x4[gbase + 32 * 256];
        float* dst = lds + khs * XQ + (c4 * 4) * XSTR;
        #pragma unroll
        for (int p = 0; p < 2; ++p) {
            const int r = row + 32 * p;
            dst[0 * XSTR + r] = xg[p].x;
            dst[1 * XSTR + r] = xg[p].y;
            dst[2 * XSTR + r] = xg[p].z;
            dst[3 * XSTR + r] = xg[p].w;
        }
    }
    __syncthreads();

    // ---- main loop over 8 chunks of 32 k ----------------------------------
    for (int c = 0; c < 8; ++c) {
        if (c < 7)  { // issue loads for next chunk (latency hidden by compute)
            xg[0] = x4[gbase + (size_t)(c + 1) * 8];
            xg[1] = x4[gbase + (size_t)(c + 1) * 8 + 32 * 256];
        }

        const float*  lx  = lds + ((c & 1) * 4 + khs) * XQ;
        const float4* wr0 = reinterpret_cast<const float4*>(Wpp)
                          + ((gs * D_MODEL + khs * 256 + c * KC) << 2) + lz;
        if (gs == 1)      proj_chunk<1>(lx, wr0, lane, acc, st);
        else if (gs == 2) proj_chunk<2>(lx, wr0, lane, acc, st);
        else              proj_chunk<0>(lx, wr0, lane, acc, st);

        if (c < 7) {
            float* dst = lds + (((c + 1) & 1) * 4 + khs) * XQ + (c4 * 4) * XSTR;
            #pragma unroll
            for (int p = 0; p < 2; ++p) {
                const int r = row + 32 * p;
                dst[0 * XSTR + r] = xg[p].x;
                dst[1 * XSTR + r] = xg[p].y;
                dst[2 * XSTR + r] = xg[p].z;
                dst[3 * XSTR + r] = xg[p].w;
            }
        }
        __syncthreads();
    }

    // ---- phased combine of K-quarters into Sb ------------------------------
    if (kh == 0) {
        #pragma unroll
        for (int i = 0; i < 13; ++i) Sb[lane * SSTR + g * 13 + i] = acc[i];
        if (g == 1) Sb[lane * SSTR + 52] = st;
        if (g == 2) Sb[lane * SSTR + 53] = st;
    }
    __syncthreads();
    #pragma unroll
    for (int ph = 1; ph < 4; ++ph) {
        if (kh == ph) {
            #pragma unroll
            for (int i = 0; i < 13; ++i) Sb[lane * SSTR + g * 13 + i] += acc[i];
            if (g == 1) Sb[lane * SSTR + 52] += st;
            if (g == 2) Sb[lane * SSTR + 53] += st;
        }
        __syncthreads();
    }

    // ---- epilogue: per-token softmax / sigmoid + writes --------------------
    if (tid < 256) {
        const int t  = tid & 63;
        const int q  = tid >> 6;
        const int tg = blockIdx.x * 64 + t;
        const float* St = Sb + t * SSTR;

        const float tsum = St[52], tss = St[53];
        const float mu  = tsum * (1.f / D_MODEL);
        const float var = tss * (1.f / D_MODEL) - mu * mu;
        const float rs  = rsqrtf(var + LN_EPS);

        if (q == 0) {
            float lg[8];
            #pragma unroll
            for (int r = 0; r < 8; ++r)
                lg[r] = rs * (St[r] - mu * c1[r]) + c2[r];
            float m = lg[0];
            #pragma unroll
            for (int r = 1; r < 8; ++r) m = fmaxf(m, lg[r]);
            float sm = 0.f;
            #pragma unroll
            for (int r = 0; r < 8; ++r) { lg[r] = expf(lg[r] - m); sm += lg[r]; }
            float inv = 1.f / sm;
            float4* o = reinterpret_cast<float4*>(rw_o + (size_t)tg * 8);
            o[0] = make_float4(lg[0]*inv, lg[1]*inv, lg[2]*inv, lg[3]*inv);
            o[1] = make_float4(lg[4]*inv, lg[5]*inv, lg[6]*inv, lg[7]*inv);
        } else if (q == 1) {
            float lg[8];
            #pragma unroll
            for (int r = 0; r < 8; ++r)
                lg[r] = rs * (St[8 + r] - mu * c1[8 + r]) + c2[8 + r];
            float gl = rs * (St[16] - mu * c1[16]) + c2[16];
            float m = lg[0];
            #pragma unroll
            for (int r = 1; r < 8; ++r) m = fmaxf(m, lg[r]);
            float sm = 0.f;
            #pragma unroll
            for (int r = 0; r < 8; ++r) { lg[r] = expf(lg[r] - m); sm += lg[r]; }
            float inv = sigmoidf(gl) / sm;
            float4* o = reinterpret_cast<float4*>(us_o + (size_t)tg * 8);
            o[0] = make_float4(lg[0]*inv, lg[1]*inv, lg[2]*inv, lg[3]*inv);
            o[1] = make_float4(lg[4]*inv, lg[5]*inv, lg[6]*inv, lg[7]*inv);
        } else {
            const int f0 = 17 + (q - 2) * 16;
            float4* o = reinterpret_cast<float4*>(wv_o + (size_t)tg * 32 + (q - 2) * 16);
            #pragma unroll
            for (int jq = 0; jq < 4; ++jq) {
                float v0 = rs * (St[f0 + jq*4 + 0] - mu * c1[f0 + jq*4 + 0]) + c2[f0 + jq*4 + 0];
                float v1 = rs * (St[f0 + jq*4 + 1] - mu * c1[f0 + jq*4 + 1]) + c2[f0 + jq*4 + 1];
                float v2 = rs * (St[f0 + jq*4 + 2] - mu * c1[f0 + jq*4 + 2]) + c2[f0 + jq*4 + 2];
                float v3 = rs * (St[f0 + jq*4 + 3] - mu * c1[f0 + jq*4 + 3]) + c2[f0 + jq*4 + 3];
                o[jq] = make_float4(v0, v1, v2, v3);
            }
        }
    }
}

// ---------------------------------------------------------------------------
// Scan phase 1: per (b,r,chunk) compute A = prod(1-us),
// B[k] = sum_t (prod_{t'>t}(1-us)) * us_t * wv_t[k].
// ---------------------------------------------------------------------------
__global__ __launch_bounds__(256) void k_chunk(
    const float* __restrict__ us, const float* __restrict__ wv,
    float* __restrict__ A, float* __restrict__ Bc)
{
    const int gid  = blockIdx.x * 256 + threadIdx.x;
    const int k    = gid & 31;
    const int unit = gid >> 5;        // (b*8+r)*64 + ch
    const int ch   = unit & 63;
    const int br   = unit >> 6;
    const int b    = br >> 3, r = br & 7;
    const int t0   = ch * CHUNK;

    const float* usp = us + ((size_t)(b * L_SEQ + t0)) * 8 + r;
    const float* wvp = wv + ((size_t)(b * L_SEQ + t0)) * 32 + k;

    float Aacc = 1.f, Bacc = 0.f;
    #pragma unroll 4
    for (int t = 0; t < CHUNK; ++t) {
        float u = usp[t * 8];
        float w = wvp[t * 32];
        float a = 1.f - u;
        Aacc *= a;
        Bacc = a * Bacc + u * w;
    }
    Bc[(size_t)unit * 32 + k] = Bacc;
    if (k == 0) A[unit] = Aacc;
}

// ---------------------------------------------------------------------------
// Scan phase 2: serial chain over 64 chunks per (b,r,k). 32 blocks x 64 thr.
// ---------------------------------------------------------------------------
__global__ __launch_bounds__(64) void k_chain(
    const float* __restrict__ A, const float* __restrict__ Bc,
    float* __restrict__ S0)
{
    const int gid = blockIdx.x * 64 + threadIdx.x;     // 0..2047
    const int k   = gid & 31;
    const int br  = gid >> 5;                          // 0..63
    float st = 0.f;
    #pragma unroll 4
    for (int ch = 0; ch < N_CHUNK; ++ch) {
        const int unit = br * N_CHUNK + ch;
        S0[(size_t)unit * 32 + k] = st;
        st = A[unit] * st + Bc[(size_t)unit * 32 + k];
    }
}

// ---------------------------------------------------------------------------
// Scan phase 3: replay each chunk from its start state, emitting
// r_v[t][k] = sum_r rw[t][r] * s_r[k]. 256 blocks x 64 threads.
// ---------------------------------------------------------------------------
__global__ __launch_bounds__(64) void k_replay(
    const float* __restrict__ rw, const float* __restrict__ us,
    const float* __restrict__ wv, const float* __restrict__ S0,
    float* __restrict__ rvs)
{
    const int gid  = blockIdx.x * 64 + threadIdx.x;
    const int k    = gid & 31;
    const int unit = gid >> 5;        // b*64 + ch
    const int ch   = unit & 63;
    const int b    = unit >> 6;

    float s[8];
    #pragma unroll
    for (int r = 0; r < 8; ++r)
        s[r] = S0[((size_t)((b * 8 + r) * N_CHUNK) + ch) * 32 + k];

    const int t0 = b * L_SEQ + ch * CHUNK;
    const float* rwp = rw + (size_t)t0 * 8;
    const float* usp = us + (size_t)t0 * 8;
    const float* wvp = wv + (size_t)t0 * 32 + k;
    float*       rvp = rvs + (size_t)t0 * 32 + k;

    for (int t = 0; t < CHUNK; ++t) {
        float4 rw0 = reinterpret_cast<const float4*>(rwp + t * 8)[0];
        float4 rw1 = reinterpret_cast<const float4*>(rwp + t * 8)[1];
        float4 us0 = reinterpret_cast<const float4*>(usp + t * 8)[0];
        float4 us1 = reinterpret_cast<const float4*>(usp + t * 8)[1];
        float  w   = wvp[t * 32];

        float rv = rw0.x*s[0] + rw0.y*s[1] + rw0.z*s[2] + rw0.w*s[3]
                 + rw1.x*s[4] + rw1.y*s[5] + rw1.z*s[6] + rw1.w*s[7];
        rvp[t * 32] = rv;

        s[0] = (1.f - us0.x)*s[0] + us0.x*w;
        s[1] = (1.f - us0.y)*s[1] + us0.y*w;
        s[2] = (1.f - us0.z)*s[2] + us0.z*w;
        s[3] = (1.f - us0.w)*s[3] + us0.w*w;
        s[4] = (1.f - us1.x)*s[4] + us1.x*w;
        s[5] = (1.f - us1.y)*s[5] + us1.y*w;
        s[6] = (1.f - us1.z)*s[6] + us1.z*w;
        s[7] = (1.f - us1.w)*s[7] + us1.w*w;
    }
}

// ---------------------------------------------------------------------------
// out[b,t,d] = mix * (sum_k rvs[b,t,k] * Wrp[d,k] + brp[d]).
// ---------------------------------------------------------------------------
__global__ __launch_bounds__(256) void k_outproj(
    const float* __restrict__ rvs, const float* __restrict__ Wrp,
    const float* __restrict__ brp, const float* __restrict__ mix_p,
    float* __restrict__ out)
{
    const int d    = blockIdx.y * 256 + threadIdx.x;
    const int tok0 = blockIdx.x * 64;

    float4 wr[8];
    #pragma unroll
    for (int q = 0; q < 8; ++q)
        wr[q] = reinterpret_cast<const float4*>(Wrp)[(size_t)d * 8 + q];

    const float bias = brp[d];
    const float mix  = mix_p[0];

    for (int t = 0; t < 64; ++t) {
        const float4* rv = reinterpret_cast<const float4*>(rvs + (size_t)(tok0 + t) * 32);
        float acc = 0.f;
        #pragma unroll
        for (int q = 0; q < 8; ++q) {
            float4 v = rv[q];
            acc += wr[q].x*v.x + wr[q].y*v.y + wr[q].z*v.z + wr[q].w*v.w;
        }
        out[(size_t)(tok0 + t) * D_MODEL + d] = mix * (acc + bias);
    }
}

// ---------------------------------------------------------------------------
extern "C" void kernel_launch(void* const* d_in, const int* in_sizes, int n_in,
                              void* d_out, int out_size, void* d_ws, size_t ws_size,
                              hipStream_t stream)
{
    const float* x    = (const float*)d_in[0];
    const float* ln_w = (const float*)d_in[1];
    const float* ln_b = (const float*)d_in[2];
    const float* Wrq  = (const float*)d_in[3];
    const float* brq  = (const float*)d_in[4];
    const float* Wrp  = (const float*)d_in[5];
    const float* brp  = (const float*)d_in[6];
    const float* Wwq  = (const float*)d_in[7];
    const float* bwq  = (const float*)d_in[8];
    const float* Wwv  = (const float*)d_in[9];
    const float* bwv  = (const float*)d_in[10];
    const float* Wwg  = (const float*)d_in[11];
    const float* bwg  = (const float*)d_in[12];
    const float* mix  = (const float*)d_in[13];
    float* out = (float*)d_out;

    // workspace layout (floats)
    float* ws   = (float*)d_ws;
    float* rw_b = ws;                 // 16384*8   = 131072
    float* us_b = ws + 131072;        // 16384*8   = 131072
    float* wv_b = ws + 262144;        // 16384*32  = 524288
    float* A_b  = ws + 786432;        // 8*8*64    = 4096
    float* B_b  = ws + 790528;        // 8*8*64*32 = 131072
    float* S0_b = ws + 921600;        // 8*8*64*32 = 131072
    float* rv_b = ws + 1052672;       // 16384*32  = 524288
    // Wpp/c1/c2 overlap rv_b: consumed by k_lnproj4 before k_replay writes rv_b
    float* Wpp  = rv_b;               // 4*1024*16 = 65536 floats
    float* c1_b = rv_b + 65536;       // 64 (52 used)
    float* c2_b = rv_b + 65600;       // 64 (52 used)

    const size_t lds_bytes = (size_t)(2 * 4 * XQ + 64 * SSTR) * 4;  // 81152 B

    k_prep<<<52, 256, 0, stream>>>(ln_w, ln_b, Wrq, brq, Wwq, bwq,
                                   Wwv, bwv, Wwg, bwg, Wpp, c1_b, c2_b);
    k_lnproj4<<<256, 1024, lds_bytes, stream>>>(x, Wpp, c1_b, c2_b,
                                                rw_b, us_b, wv_b);
    k_chunk <<<512, 256, 0, stream>>>(us_b, wv_b, A_b, B_b);
    k_chain <<<32,  64,  0, stream>>>(A_b, B_b, S0_b);
    k_replay<<<256, 64,  0, stream>>>(rw_b, us_b, wv_b, S0_b, rv_b);
    dim3 gc(N_TOK / 64, 4);
    k_outproj<<<gc, 256, 0, stream>>>(rv_b, Wrp, brp, mix, out);
}

// Round 9
// 105.176 us; speedup vs baseline: 1.5277x; 1.5277x over previous
//
#include <hip/hip_runtime.h>

#define D_MODEL 1024
#define L_SEQ   2048
#define N_BATCH 8
#define N_TOK   (N_BATCH * L_SEQ)   // 16384
#define N_REGS  8
#define D_REG   32
#define LN_EPS  1e-5f

// LDS geometry for k_lnproj3
#define KC      32                  // k-chunk size
#define XSTR    65                  // padded token stride (odd -> conflict-free)
#define XQ      (KC * XSTR)         // dwords per (buffer, quarter) = 2080
#define SSTR    57                  // epilogue tile stride (57%32=25, gcd=1)

// scan geometry: 16-step half-chunks
#define HSTEP   16
#define N_HALF  128                 // per (b,r): 2048 / 16

__device__ __forceinline__ float wred(float v) {
    #pragma unroll
    for (int off = 32; off > 0; off >>= 1) v += __shfl_xor(v, off, 64);
    return v;
}

__device__ __forceinline__ float sigmoidf(float z) {
    return 1.f / (1.f + expf(-z));
}

// ---------------------------------------------------------------------------
// Prep: fold ln_w into all 49 projection rows, pack as Wpp[g][k][16] with
// features f = g*13+i (i<13; f>=49 zero pads); c1[f] = sum_k W[f,k]*ln_w[k],
// c2[f] = sum_k W[f,k]*ln_b[k] + bias[f].
// Feature order: 0..7 = Wrq, 8..15 = Wwq, 16 = Wwg, 17..48 = Wwv.
// ---------------------------------------------------------------------------
__global__ __launch_bounds__(256) void k_prep(
    const float* __restrict__ ln_w, const float* __restrict__ ln_b,
    const float* __restrict__ Wrq,  const float* __restrict__ brq,
    const float* __restrict__ Wwq,  const float* __restrict__ bwq,
    const float* __restrict__ Wwv,  const float* __restrict__ bwv,
    const float* __restrict__ Wwg,  const float* __restrict__ bwg,
    float* __restrict__ Wpp, float* __restrict__ c1, float* __restrict__ c2)
{
    const int f = blockIdx.x;            // 0..51
    const int g = f / 13, i = f % 13;

    const float* wrow = nullptr; float bias = 0.f;
    if (f < 8)        { wrow = Wrq + f * D_MODEL;        bias = brq[f]; }
    else if (f < 16)  { wrow = Wwq + (f - 8) * D_MODEL;  bias = bwq[f - 8]; }
    else if (f == 16) { wrow = Wwg;                      bias = bwg[0]; }
    else if (f < 49)  { wrow = Wwv + (f - 17) * D_MODEL; bias = bwv[f - 17]; }

    float p1 = 0.f, p2 = 0.f;
    #pragma unroll
    for (int j = 0; j < 4; ++j) {
        const int k = j * 256 + threadIdx.x;
        float w  = wrow ? wrow[k] : 0.f;
        float wg = w * ln_w[k];
        Wpp[((size_t)(g * D_MODEL + k)) * 16 + i] = wg;
        p1 += wg;
        p2 = fmaf(w, ln_b[k], p2);
    }
    p1 = wred(p1); p2 = wred(p2);

    __shared__ float r1[4], r2[4];
    const int l = threadIdx.x & 63, w = threadIdx.x >> 6;
    if (l == 0) { r1[w] = p1; r2[w] = p2; }
    __syncthreads();
    if (threadIdx.x == 0) {
        c1[f] = r1[0] + r1[1] + r1[2] + r1[3];
        c2[f] = r2[0] + r2[1] + r2[2] + r2[3] + bias;
    }
}

// ---------------------------------------------------------------------------
// Inner projection loop over one 32-k LDS chunk. STATS: 0=none, 1=sum, 2=ss.
// Weights via wave-uniform scalar loads (s_load path — round-7 proven).
// ---------------------------------------------------------------------------
template<int STATS>
__device__ __forceinline__ void proj_chunk(
    const float* __restrict__ lx,      // LDS base: + k*XSTR + lane
    const float4* __restrict__ wr0,    // Wpp record base for this chunk
    int lane, float acc[13], float& st)
{
    #pragma unroll 4
    for (int k = 0; k < KC; ++k) {
        const float xs = lx[k * XSTR + lane];
        const float4* wr = wr0 + (k << 2);
        float4 wa = wr[0], wb = wr[1], wc = wr[2];
        float  wd = reinterpret_cast<const float*>(wr)[12];
        acc[0]  = fmaf(xs, wa.x, acc[0]);
        acc[1]  = fmaf(xs, wa.y, acc[1]);
        acc[2]  = fmaf(xs, wa.z, acc[2]);
        acc[3]  = fmaf(xs, wa.w, acc[3]);
        acc[4]  = fmaf(xs, wb.x, acc[4]);
        acc[5]  = fmaf(xs, wb.y, acc[5]);
        acc[6]  = fmaf(xs, wb.z, acc[6]);
        acc[7]  = fmaf(xs, wb.w, acc[7]);
        acc[8]  = fmaf(xs, wc.x, acc[8]);
        acc[9]  = fmaf(xs, wc.y, acc[9]);
        acc[10] = fmaf(xs, wc.z, acc[10]);
        acc[11] = fmaf(xs, wc.w, acc[11]);
        acc[12] = fmaf(xs, wd,   acc[12]);
        if (STATS == 1) st += xs;
        if (STATS == 2) st = fmaf(xs, xs, st);
    }
}

// ---------------------------------------------------------------------------
// Kernel A v3 (round-7 proven): LDS-transpose-staged x, scalar-path weights.
// Block = 1024 thr = 16 waves (4 feature-groups g x 4 K-quarters kh),
// 64 tokens per block, lane = token. Dynamic LDS: 2*4*XQ + 64*SSTR dwords.
// ---------------------------------------------------------------------------
__global__ __launch_bounds__(1024) void k_lnproj3(
    const float* __restrict__ x,
    const float* __restrict__ Wpp,
    const float* __restrict__ c1, const float* __restrict__ c2,
    float* __restrict__ rw_o, float* __restrict__ us_o, float* __restrict__ wv_o)
{
    extern __shared__ float lds[];
    float* Sb = lds + 2 * 4 * XQ;       // [64][SSTR]

    const int tid  = threadIdx.x;
    const int lane = tid & 63;
    const int wv   = tid >> 6;          // 0..15
    const int g    = wv & 3;            // feature group
    const int kh   = wv >> 2;           // K quarter
    const int tok0 = blockIdx.x * 64;

    const int gs  = __builtin_amdgcn_readfirstlane(g);
    const int khs = __builtin_amdgcn_readfirstlane(kh);

    // staging ids within the 256-thread quarter-group
    const int tq  = tid & 255;
    const int row = tq >> 3;            // 0..31 (token), +32 on pass 1
    const int c4  = tq & 7;             // float4 column (k_local = c4*4)

    const float4* x4 = reinterpret_cast<const float4*>(x);

    float4 xg[2];
    float acc[13];
    #pragma unroll
    for (int i = 0; i < 13; ++i) acc[i] = 0.f;
    float st = 0.f;

    const size_t gbase = (size_t)(tok0 + row) * 256 + khs * 64 + c4;

    // ---- prologue: stage chunk 0 ------------------------------------------
    {
        xg[0] = x4[gbase];
        xg[1] = x4[gbase + 32 * 256];
        float* dst = lds + khs * XQ + (c4 * 4) * XSTR;
        #pragma unroll
        for (int p = 0; p < 2; ++p) {
            const int r = row + 32 * p;
            dst[0 * XSTR + r] = xg[p].x;
            dst[1 * XSTR + r] = xg[p].y;
            dst[2 * XSTR + r] = xg[p].z;
            dst[3 * XSTR + r] = xg[p].w;
        }
    }
    __syncthreads();

    // ---- main loop over 8 chunks of 32 k ----------------------------------
    for (int c = 0; c < 8; ++c) {
        if (c < 7)  { // issue loads for next chunk (latency hidden by compute)
            xg[0] = x4[gbase + (size_t)(c + 1) * 8];
            xg[1] = x4[gbase + (size_t)(c + 1) * 8 + 32 * 256];
        }

        const float*  lx  = lds + ((c & 1) * 4 + khs) * XQ;
        const float4* wr0 = reinterpret_cast<const float4*>(Wpp)
                          + ((gs * D_MODEL + khs * 256 + c * KC) << 2);
        if (gs == 1)      proj_chunk<1>(lx, wr0, lane, acc, st);
        else if (gs == 2) proj_chunk<2>(lx, wr0, lane, acc, st);
        else              proj_chunk<0>(lx, wr0, lane, acc, st);

        if (c < 7) {
            float* dst = lds + (((c + 1) & 1) * 4 + khs) * XQ + (c4 * 4) * XSTR;
            #pragma unroll
            for (int p = 0; p < 2; ++p) {
                const int r = row + 32 * p;
                dst[0 * XSTR + r] = xg[p].x;
                dst[1 * XSTR + r] = xg[p].y;
                dst[2 * XSTR + r] = xg[p].z;
                dst[3 * XSTR + r] = xg[p].w;
            }
        }
        __syncthreads();
    }

    // ---- phased combine of K-quarters into Sb ------------------------------
    if (kh == 0) {
        #pragma unroll
        for (int i = 0; i < 13; ++i) Sb[lane * SSTR + g * 13 + i] = acc[i];
        if (g == 1) Sb[lane * SSTR + 52] = st;
        if (g == 2) Sb[lane * SSTR + 53] = st;
    }
    __syncthreads();
    #pragma unroll
    for (int ph = 1; ph < 4; ++ph) {
        if (kh == ph) {
            #pragma unroll
            for (int i = 0; i < 13; ++i) Sb[lane * SSTR + g * 13 + i] += acc[i];
            if (g == 1) Sb[lane * SSTR + 52] += st;
            if (g == 2) Sb[lane * SSTR + 53] += st;
        }
        __syncthreads();
    }

    // ---- epilogue: per-token softmax / sigmoid + writes --------------------
    if (tid < 256) {
        const int t  = tid & 63;
        const int q  = tid >> 6;
        const int tg = blockIdx.x * 64 + t;
        const float* St = Sb + t * SSTR;

        const float tsum = St[52], tss = St[53];
        const float mu  = tsum * (1.f / D_MODEL);
        const float var = tss * (1.f / D_MODEL) - mu * mu;
        const float rs  = rsqrtf(var + LN_EPS);

        if (q == 0) {
            float lg[8];
            #pragma unroll
            for (int r = 0; r < 8; ++r)
                lg[r] = rs * (St[r] - mu * c1[r]) + c2[r];
            float m = lg[0];
            #pragma unroll
            for (int r = 1; r < 8; ++r) m = fmaxf(m, lg[r]);
            float sm = 0.f;
            #pragma unroll
            for (int r = 0; r < 8; ++r) { lg[r] = expf(lg[r] - m); sm += lg[r]; }
            float inv = 1.f / sm;
            float4* o = reinterpret_cast<float4*>(rw_o + (size_t)tg * 8);
            o[0] = make_float4(lg[0]*inv, lg[1]*inv, lg[2]*inv, lg[3]*inv);
            o[1] = make_float4(lg[4]*inv, lg[5]*inv, lg[6]*inv, lg[7]*inv);
        } else if (q == 1) {
            float lg[8];
            #pragma unroll
            for (int r = 0; r < 8; ++r)
                lg[r] = rs * (St[8 + r] - mu * c1[8 + r]) + c2[8 + r];
            float gl = rs * (St[16] - mu * c1[16]) + c2[16];
            float m = lg[0];
            #pragma unroll
            for (int r = 1; r < 8; ++r) m = fmaxf(m, lg[r]);
            float sm = 0.f;
            #pragma unroll
            for (int r = 0; r < 8; ++r) { lg[r] = expf(lg[r] - m); sm += lg[r]; }
            float inv = sigmoidf(gl) / sm;
            float4* o = reinterpret_cast<float4*>(us_o + (size_t)tg * 8);
            o[0] = make_float4(lg[0]*inv, lg[1]*inv, lg[2]*inv, lg[3]*inv);
            o[1] = make_float4(lg[4]*inv, lg[5]*inv, lg[6]*inv, lg[7]*inv);
        } else {
            const int f0 = 17 + (q - 2) * 16;
            float4* o = reinterpret_cast<float4*>(wv_o + (size_t)tg * 32 + (q - 2) * 16);
            #pragma unroll
            for (int jq = 0; jq < 4; ++jq) {
                float v0 = rs * (St[f0 + jq*4 + 0] - mu * c1[f0 + jq*4 + 0]) + c2[f0 + jq*4 + 0];
                float v1 = rs * (St[f0 + jq*4 + 1] - mu * c1[f0 + jq*4 + 1]) + c2[f0 + jq*4 + 1];
                float v2 = rs * (St[f0 + jq*4 + 2] - mu * c1[f0 + jq*4 + 2]) + c2[f0 + jq*4 + 2];
                float v3 = rs * (St[f0 + jq*4 + 3] - mu * c1[f0 + jq*4 + 3]) + c2[f0 + jq*4 + 3];
                o[jq] = make_float4(v0, v1, v2, v3);
            }
        }
    }
}

// ---------------------------------------------------------------------------
// Fused scan (chunk-compose + chain), one block per (b,r). 64 blocks x 1024.
// Phase A: per 16-step half-chunk h (128 per block) and k: A = prod(1-u),
//          B[k] = sum_t prod_{t'>t}(1-u) * u_t * wv_t[k]  -> LDS.
// Phase B: 32 threads chain serially over the 128 halves, emitting the
//          register state at each half start to S0[(b,r), h, k] (global).
// us is LDS-staged once (coalesced) so phase A's only global loads are wv.
// ---------------------------------------------------------------------------
__global__ __launch_bounds__(1024) void k_scan(
    const float* __restrict__ us, const float* __restrict__ wv,
    float* __restrict__ S0)
{
    __shared__ float S_us[L_SEQ];           // 8 KB
    __shared__ float lA[N_HALF];            // 0.5 KB
    __shared__ float lB[N_HALF * 32];       // 16 KB

    const int tid = threadIdx.x;
    const int b   = blockIdx.x >> 3;
    const int r   = blockIdx.x & 7;

    // stage us[b, :, r]
    #pragma unroll
    for (int i = 0; i < 2; ++i) {
        const int t = i * 1024 + tid;
        S_us[t] = us[((size_t)(b * L_SEQ + t)) * 8 + r];
    }
    __syncthreads();

    // phase A: thread -> k = tid&31, halves hb..hb+3
    const int k  = tid & 31;
    const int hb = (tid >> 5) * 4;
    #pragma unroll
    for (int j = 0; j < 4; ++j) {
        const int h  = hb + j;
        const int t0 = h * HSTEP;
        const float* wvp = wv + ((size_t)(b * L_SEQ + t0)) * 32 + k;

        float Aacc = 1.f, Bacc = 0.f;
        #pragma unroll
        for (int gq = 0; gq < 2; ++gq) {
            float wl[8], ul[8];
            #pragma unroll
            for (int e = 0; e < 8; ++e) {
                wl[e] = wvp[(gq * 8 + e) * 32];
                ul[e] = S_us[t0 + gq * 8 + e];
            }
            #pragma unroll
            for (int e = 0; e < 8; ++e) {
                float a = 1.f - ul[e];
                Aacc *= a;
                Bacc = fmaf(a, Bacc, ul[e] * wl[e]);
            }
        }
        lB[h * 32 + k] = Bacc;
        if (k == 0) lA[h] = Aacc;
    }
    __syncthreads();

    // phase B: serial chain over halves
    if (tid < 32) {
        float stv = 0.f;
        float* S0p = S0 + ((size_t)(b * 8 + r) * N_HALF) * 32 + tid;
        for (int h = 0; h < N_HALF; ++h) {
            S0p[h * 32] = stv;
            stv = fmaf(lA[h], stv, lB[h * 32 + tid]);
        }
    }
}

// ---------------------------------------------------------------------------
// Replay each 16-step half-chunk from its start state, emitting
// r_v[t][k] = sum_r rw[t][r] * s_r[k] (read BEFORE update).
// 128 blocks x 256 thr; thread = (half-unit hu, k). Loads 4-deep pipelined.
// ---------------------------------------------------------------------------
__global__ __launch_bounds__(256) void k_replay2(
    const float* __restrict__ rw, const float* __restrict__ us,
    const float* __restrict__ wv, const float* __restrict__ S0,
    float* __restrict__ rvs)
{
    const int gid = blockIdx.x * 256 + threadIdx.x;   // 0..32767
    const int k   = gid & 31;
    const int hu  = gid >> 5;        // 0..1023: b*128 + ch2
    const int b   = hu >> 7;
    const int ch2 = hu & 127;

    float s[8];
    #pragma unroll
    for (int r = 0; r < 8; ++r)
        s[r] = S0[((size_t)((b * 8 + r) * N_HALF) + ch2) * 32 + k];

    const int t0 = b * L_SEQ + ch2 * HSTEP;
    const float* rwp = rw + (size_t)t0 * 8;
    const float* usp = us + (size_t)t0 * 8;
    const float* wvp = wv + (size_t)t0 * 32 + k;
    float*       rvp = rvs + (size_t)t0 * 32 + k;

    #pragma unroll
    for (int g4 = 0; g4 < 4; ++g4) {
        float4 r0[4], r1[4], u0[4], u1[4];
        float  wl[4];
        #pragma unroll
        for (int j = 0; j < 4; ++j) {
            const int t = g4 * 4 + j;
            r0[j] = reinterpret_cast<const float4*>(rwp + t * 8)[0];
            r1[j] = reinterpret_cast<const float4*>(rwp + t * 8)[1];
            u0[j] = reinterpret_cast<const float4*>(usp + t * 8)[0];
            u1[j] = reinterpret_cast<const float4*>(usp + t * 8)[1];
            wl[j] = wvp[t * 32];
        }
        #pragma unroll
        for (int j = 0; j < 4; ++j) {
            const int t = g4 * 4 + j;
            float rv = r0[j].x*s[0] + r0[j].y*s[1] + r0[j].z*s[2] + r0[j].w*s[3]
                     + r1[j].x*s[4] + r1[j].y*s[5] + r1[j].z*s[6] + r1[j].w*s[7];
            rvp[t * 32] = rv;
            const float w = wl[j];
            s[0] = fmaf(u0[j].x, w - s[0], s[0]);
            s[1] = fmaf(u0[j].y, w - s[1], s[1]);
            s[2] = fmaf(u0[j].z, w - s[2], s[2]);
            s[3] = fmaf(u0[j].w, w - s[3], s[3]);
            s[4] = fmaf(u1[j].x, w - s[4], s[4]);
            s[5] = fmaf(u1[j].y, w - s[5], s[5]);
            s[6] = fmaf(u1[j].z, w - s[6], s[6]);
            s[7] = fmaf(u1[j].w, w - s[7], s[7]);
        }
    }
}

// ---------------------------------------------------------------------------
// out[tok, d] = mix * (sum_k rvs[tok,k] * Wrp[d,k] + brp[d]).
// Thread owns 4 consecutive d (Wrp rows in regs), float4 stores.
// Grid 256 blocks x 256 thr; block covers 64 tokens x all 1024 d.
// ---------------------------------------------------------------------------
__global__ __launch_bounds__(256) void k_outproj2(
    const float* __restrict__ rvs, const float* __restrict__ Wrp,
    const float* __restrict__ brp, const float* __restrict__ mix_p,
    float* __restrict__ out)
{
    const int d0   = threadIdx.x * 4;
    const int tok0 = blockIdx.x * 64;

    float4 wr[4][8];
    #pragma unroll
    for (int i = 0; i < 4; ++i)
        #pragma unroll
        for (int q = 0; q < 8; ++q)
            wr[i][q] = reinterpret_cast<const float4*>(Wrp)[(size_t)(d0 + i) * 8 + q];

    const float4 bias = *reinterpret_cast<const float4*>(brp + d0);
    const float  mix  = mix_p[0];

    for (int t = 0; t < 64; ++t) {
        const float4* rv = reinterpret_cast<const float4*>(rvs + (size_t)(tok0 + t) * 32);
        float4 v[8];
        #pragma unroll
        for (int q = 0; q < 8; ++q) v[q] = rv[q];

        float acc[4] = {0.f, 0.f, 0.f, 0.f};
        #pragma unroll
        for (int i = 0; i < 4; ++i)
            #pragma unroll
            for (int q = 0; q < 8; ++q)
                acc[i] += wr[i][q].x*v[q].x + wr[i][q].y*v[q].y
                        + wr[i][q].z*v[q].z + wr[i][q].w*v[q].w;

        float4 o = make_float4(mix * (acc[0] + bias.x), mix * (acc[1] + bias.y),
                               mix * (acc[2] + bias.z), mix * (acc[3] + bias.w));
        *reinterpret_cast<float4*>(out + (size_t)(tok0 + t) * D_MODEL + d0) = o;
    }
}

// ---------------------------------------------------------------------------
extern "C" void kernel_launch(void* const* d_in, const int* in_sizes, int n_in,
                              void* d_out, int out_size, void* d_ws, size_t ws_size,
                              hipStream_t stream)
{
    const float* x    = (const float*)d_in[0];
    const float* ln_w = (const float*)d_in[1];
    const float* ln_b = (const float*)d_in[2];
    const float* Wrq  = (const float*)d_in[3];
    const float* brq  = (const float*)d_in[4];
    const float* Wrp  = (const float*)d_in[5];
    const float* brp  = (const float*)d_in[6];
    const float* Wwq  = (const float*)d_in[7];
    const float* bwq  = (const float*)d_in[8];
    const float* Wwv  = (const float*)d_in[9];
    const float* bwv  = (const float*)d_in[10];
    const float* Wwg  = (const float*)d_in[11];
    const float* bwg  = (const float*)d_in[12];
    const float* mix  = (const float*)d_in[13];
    float* out = (float*)d_out;

    // workspace layout (floats)
    float* ws   = (float*)d_ws;
    float* rw_b = ws;                 // 16384*8      = 131072
    float* us_b = ws + 131072;        // 16384*8      = 131072
    float* wv_b = ws + 262144;        // 16384*32     = 524288
    float* S0_b = ws + 786432;        // 8*8*128*32   = 262144
    float* rv_b = ws + 1048576;       // 16384*32     = 524288
    // Wpp/c1/c2 overlay rv_b: consumed by k_lnproj3 before k_replay2 writes rv_b
    float* Wpp  = rv_b;               // 4*1024*16 = 65536 floats
    float* c1_b = rv_b + 65536;       // 64 (52 used)
    float* c2_b = rv_b + 65600;       // 64 (52 used)
    // total: 1572864 floats = 6.0 MiB

    const size_t lds_bytes = (size_t)(2 * 4 * XQ + 64 * SSTR) * 4;  // 81152 B

    k_prep<<<52, 256, 0, stream>>>(ln_w, ln_b, Wrq, brq, Wwq, bwq,
                                   Wwv, bwv, Wwg, bwg, Wpp, c1_b, c2_b);
    k_lnproj3<<<256, 1024, lds_bytes, stream>>>(x, Wpp, c1_b, c2_b,
                                                rw_b, us_b, wv_b);
    k_scan   <<<64, 1024, 0, stream>>>(us_b, wv_b, S0_b);
    k_replay2<<<128, 256, 0, stream>>>(rw_b, us_b, wv_b, S0_b, rv_b);
    k_outproj2<<<256, 256, 0, stream>>>(rv_b, Wrp, brp, mix, out);
}

// Round 10
// 103.112 us; speedup vs baseline: 1.5583x; 1.0200x over previous
//
#include <hip/hip_runtime.h>

#define D_MODEL 1024
#define L_SEQ   2048
#define N_BATCH 8
#define N_TOK   (N_BATCH * L_SEQ)   // 16384
#define N_REGS  8
#define D_REG   32
#define LN_EPS  1e-5f

// LDS geometry for k_lnproj3
#define KC      32                  // k-chunk size
#define XSTR    65                  // padded token stride (odd -> conflict-free)
#define XQ      (KC * XSTR)         // dwords per (buffer, quarter) = 2080
#define SSTR    57                  // epilogue tile stride (57%32=25, gcd=1)

// scan geometry: 16-step half-chunks
#define HSTEP   16
#define N_HALF  128                 // per (b,r): 2048 / 16

__device__ __forceinline__ float wred(float v) {
    #pragma unroll
    for (int off = 32; off > 0; off >>= 1) v += __shfl_xor(v, off, 64);
    return v;
}

__device__ __forceinline__ float sigmoidf(float z) {
    return 1.f / (1.f + expf(-z));
}

// ---------------------------------------------------------------------------
// Prep: fold ln_w into all 49 projection rows, pack as Wpp[g][k][16] with
// features f = g*13+i (i<13; f>=49 zero pads); c1[f] = sum_k W[f,k]*ln_w[k],
// c2[f] = sum_k W[f,k]*ln_b[k] + bias[f].
// Feature order: 0..7 = Wrq, 8..15 = Wwq, 16 = Wwg, 17..48 = Wwv.
// ---------------------------------------------------------------------------
__global__ __launch_bounds__(256) void k_prep(
    const float* __restrict__ ln_w, const float* __restrict__ ln_b,
    const float* __restrict__ Wrq,  const float* __restrict__ brq,
    const float* __restrict__ Wwq,  const float* __restrict__ bwq,
    const float* __restrict__ Wwv,  const float* __restrict__ bwv,
    const float* __restrict__ Wwg,  const float* __restrict__ bwg,
    float* __restrict__ Wpp, float* __restrict__ c1, float* __restrict__ c2)
{
    const int f = blockIdx.x;            // 0..51
    const int g = f / 13, i = f % 13;

    const float* wrow = nullptr; float bias = 0.f;
    if (f < 8)        { wrow = Wrq + f * D_MODEL;        bias = brq[f]; }
    else if (f < 16)  { wrow = Wwq + (f - 8) * D_MODEL;  bias = bwq[f - 8]; }
    else if (f == 16) { wrow = Wwg;                      bias = bwg[0]; }
    else if (f < 49)  { wrow = Wwv + (f - 17) * D_MODEL; bias = bwv[f - 17]; }

    float p1 = 0.f, p2 = 0.f;
    #pragma unroll
    for (int j = 0; j < 4; ++j) {
        const int k = j * 256 + threadIdx.x;
        float w  = wrow ? wrow[k] : 0.f;
        float wg = w * ln_w[k];
        Wpp[((size_t)(g * D_MODEL + k)) * 16 + i] = wg;
        p1 += wg;
        p2 = fmaf(w, ln_b[k], p2);
    }
    p1 = wred(p1); p2 = wred(p2);

    __shared__ float r1[4], r2[4];
    const int l = threadIdx.x & 63, w = threadIdx.x >> 6;
    if (l == 0) { r1[w] = p1; r2[w] = p2; }
    __syncthreads();
    if (threadIdx.x == 0) {
        c1[f] = r1[0] + r1[1] + r1[2] + r1[3];
        c2[f] = r2[0] + r2[1] + r2[2] + r2[3] + bias;
    }
}

// ---------------------------------------------------------------------------
// Inner projection loop over one 32-k LDS chunk. STATS: 0=none, 1=sum, 2=ss.
// Weights via wave-uniform scalar loads (s_load path — round-7 proven).
// ---------------------------------------------------------------------------
template<int STATS>
__device__ __forceinline__ void proj_chunk(
    const float* __restrict__ lx,      // LDS base: + k*XSTR + lane
    const float4* __restrict__ wr0,    // Wpp record base for this chunk
    int lane, float acc[13], float& st)
{
    #pragma unroll 4
    for (int k = 0; k < KC; ++k) {
        const float xs = lx[k * XSTR + lane];
        const float4* wr = wr0 + (k << 2);
        float4 wa = wr[0], wb = wr[1], wc = wr[2];
        float  wd = reinterpret_cast<const float*>(wr)[12];
        acc[0]  = fmaf(xs, wa.x, acc[0]);
        acc[1]  = fmaf(xs, wa.y, acc[1]);
        acc[2]  = fmaf(xs, wa.z, acc[2]);
        acc[3]  = fmaf(xs, wa.w, acc[3]);
        acc[4]  = fmaf(xs, wb.x, acc[4]);
        acc[5]  = fmaf(xs, wb.y, acc[5]);
        acc[6]  = fmaf(xs, wb.z, acc[6]);
        acc[7]  = fmaf(xs, wb.w, acc[7]);
        acc[8]  = fmaf(xs, wc.x, acc[8]);
        acc[9]  = fmaf(xs, wc.y, acc[9]);
        acc[10] = fmaf(xs, wc.z, acc[10]);
        acc[11] = fmaf(xs, wc.w, acc[11]);
        acc[12] = fmaf(xs, wd,   acc[12]);
        if (STATS == 1) st += xs;
        if (STATS == 2) st = fmaf(xs, xs, st);
    }
}

// ---------------------------------------------------------------------------
// Kernel A v3 (round-7 proven): LDS-transpose-staged x, scalar-path weights.
// Block = 1024 thr = 16 waves (4 feature-groups g x 4 K-quarters kh),
// 64 tokens per block, lane = token. Dynamic LDS: 2*4*XQ + 64*SSTR dwords.
// ---------------------------------------------------------------------------
__global__ __launch_bounds__(1024) void k_lnproj3(
    const float* __restrict__ x,
    const float* __restrict__ Wpp,
    const float* __restrict__ c1, const float* __restrict__ c2,
    float* __restrict__ rw_o, float* __restrict__ us_o, float* __restrict__ wv_o)
{
    extern __shared__ float lds[];
    float* Sb = lds + 2 * 4 * XQ;       // [64][SSTR]

    const int tid  = threadIdx.x;
    const int lane = tid & 63;
    const int wv   = tid >> 6;          // 0..15
    const int g    = wv & 3;            // feature group
    const int kh   = wv >> 2;           // K quarter
    const int tok0 = blockIdx.x * 64;

    const int gs  = __builtin_amdgcn_readfirstlane(g);
    const int khs = __builtin_amdgcn_readfirstlane(kh);

    // staging ids within the 256-thread quarter-group
    const int tq  = tid & 255;
    const int row = tq >> 3;            // 0..31 (token), +32 on pass 1
    const int c4  = tq & 7;             // float4 column (k_local = c4*4)

    const float4* x4 = reinterpret_cast<const float4*>(x);

    float4 xg[2];
    float acc[13];
    #pragma unroll
    for (int i = 0; i < 13; ++i) acc[i] = 0.f;
    float st = 0.f;

    const size_t gbase = (size_t)(tok0 + row) * 256 + khs * 64 + c4;

    // ---- prologue: stage chunk 0 ------------------------------------------
    {
        xg[0] = x4[gbase];
        xg[1] = x4[gbase + 32 * 256];
        float* dst = lds + khs * XQ + (c4 * 4) * XSTR;
        #pragma unroll
        for (int p = 0; p < 2; ++p) {
            const int r = row + 32 * p;
            dst[0 * XSTR + r] = xg[p].x;
            dst[1 * XSTR + r] = xg[p].y;
            dst[2 * XSTR + r] = xg[p].z;
            dst[3 * XSTR + r] = xg[p].w;
        }
    }
    __syncthreads();

    // ---- main loop over 8 chunks of 32 k ----------------------------------
    for (int c = 0; c < 8; ++c) {
        if (c < 7)  { // issue loads for next chunk (latency hidden by compute)
            xg[0] = x4[gbase + (size_t)(c + 1) * 8];
            xg[1] = x4[gbase + (size_t)(c + 1) * 8 + 32 * 256];
        }

        const float*  lx  = lds + ((c & 1) * 4 + khs) * XQ;
        const float4* wr0 = reinterpret_cast<const float4*>(Wpp)
                          + ((gs * D_MODEL + khs * 256 + c * KC) << 2);
        if (gs == 1)      proj_chunk<1>(lx, wr0, lane, acc, st);
        else if (gs == 2) proj_chunk<2>(lx, wr0, lane, acc, st);
        else              proj_chunk<0>(lx, wr0, lane, acc, st);

        if (c < 7) {
            float* dst = lds + (((c + 1) & 1) * 4 + khs) * XQ + (c4 * 4) * XSTR;
            #pragma unroll
            for (int p = 0; p < 2; ++p) {
                const int r = row + 32 * p;
                dst[0 * XSTR + r] = xg[p].x;
                dst[1 * XSTR + r] = xg[p].y;
                dst[2 * XSTR + r] = xg[p].z;
                dst[3 * XSTR + r] = xg[p].w;
            }
        }
        __syncthreads();
    }

    // ---- phased combine of K-quarters into Sb ------------------------------
    if (kh == 0) {
        #pragma unroll
        for (int i = 0; i < 13; ++i) Sb[lane * SSTR + g * 13 + i] = acc[i];
        if (g == 1) Sb[lane * SSTR + 52] = st;
        if (g == 2) Sb[lane * SSTR + 53] = st;
    }
    __syncthreads();
    #pragma unroll
    for (int ph = 1; ph < 4; ++ph) {
        if (kh == ph) {
            #pragma unroll
            for (int i = 0; i < 13; ++i) Sb[lane * SSTR + g * 13 + i] += acc[i];
            if (g == 1) Sb[lane * SSTR + 52] += st;
            if (g == 2) Sb[lane * SSTR + 53] += st;
        }
        __syncthreads();
    }

    // ---- epilogue: per-token softmax / sigmoid + writes --------------------
    if (tid < 256) {
        const int t  = tid & 63;
        const int q  = tid >> 6;
        const int tg = blockIdx.x * 64 + t;
        const float* St = Sb + t * SSTR;

        const float tsum = St[52], tss = St[53];
        const float mu  = tsum * (1.f / D_MODEL);
        const float var = tss * (1.f / D_MODEL) - mu * mu;
        const float rs  = rsqrtf(var + LN_EPS);

        if (q == 0) {
            float lg[8];
            #pragma unroll
            for (int r = 0; r < 8; ++r)
                lg[r] = rs * (St[r] - mu * c1[r]) + c2[r];
            float m = lg[0];
            #pragma unroll
            for (int r = 1; r < 8; ++r) m = fmaxf(m, lg[r]);
            float sm = 0.f;
            #pragma unroll
            for (int r = 0; r < 8; ++r) { lg[r] = expf(lg[r] - m); sm += lg[r]; }
            float inv = 1.f / sm;
            float4* o = reinterpret_cast<float4*>(rw_o + (size_t)tg * 8);
            o[0] = make_float4(lg[0]*inv, lg[1]*inv, lg[2]*inv, lg[3]*inv);
            o[1] = make_float4(lg[4]*inv, lg[5]*inv, lg[6]*inv, lg[7]*inv);
        } else if (q == 1) {
            float lg[8];
            #pragma unroll
            for (int r = 0; r < 8; ++r)
                lg[r] = rs * (St[8 + r] - mu * c1[8 + r]) + c2[8 + r];
            float gl = rs * (St[16] - mu * c1[16]) + c2[16];
            float m = lg[0];
            #pragma unroll
            for (int r = 1; r < 8; ++r) m = fmaxf(m, lg[r]);
            float sm = 0.f;
            #pragma unroll
            for (int r = 0; r < 8; ++r) { lg[r] = expf(lg[r] - m); sm += lg[r]; }
            float inv = sigmoidf(gl) / sm;
            float4* o = reinterpret_cast<float4*>(us_o + (size_t)tg * 8);
            o[0] = make_float4(lg[0]*inv, lg[1]*inv, lg[2]*inv, lg[3]*inv);
            o[1] = make_float4(lg[4]*inv, lg[5]*inv, lg[6]*inv, lg[7]*inv);
        } else {
            const int f0 = 17 + (q - 2) * 16;
            float4* o = reinterpret_cast<float4*>(wv_o + (size_t)tg * 32 + (q - 2) * 16);
            #pragma unroll
            for (int jq = 0; jq < 4; ++jq) {
                float v0 = rs * (St[f0 + jq*4 + 0] - mu * c1[f0 + jq*4 + 0]) + c2[f0 + jq*4 + 0];
                float v1 = rs * (St[f0 + jq*4 + 1] - mu * c1[f0 + jq*4 + 1]) + c2[f0 + jq*4 + 1];
                float v2 = rs * (St[f0 + jq*4 + 2] - mu * c1[f0 + jq*4 + 2]) + c2[f0 + jq*4 + 2];
                float v3 = rs * (St[f0 + jq*4 + 3] - mu * c1[f0 + jq*4 + 3]) + c2[f0 + jq*4 + 3];
                o[jq] = make_float4(v0, v1, v2, v3);
            }
        }
    }
}

// ---------------------------------------------------------------------------
// Fused scan (chunk-compose + chain), one block per (b,r). 64 blocks x 1024.
// ---------------------------------------------------------------------------
__global__ __launch_bounds__(1024) void k_scan(
    const float* __restrict__ us, const float* __restrict__ wv,
    float* __restrict__ S0)
{
    __shared__ float S_us[L_SEQ];           // 8 KB
    __shared__ float lA[N_HALF];            // 0.5 KB
    __shared__ float lB[N_HALF * 32];       // 16 KB

    const int tid = threadIdx.x;
    const int b   = blockIdx.x >> 3;
    const int r   = blockIdx.x & 7;

    // stage us[b, :, r]
    #pragma unroll
    for (int i = 0; i < 2; ++i) {
        const int t = i * 1024 + tid;
        S_us[t] = us[((size_t)(b * L_SEQ + t)) * 8 + r];
    }
    __syncthreads();

    // phase A: thread -> k = tid&31, halves hb..hb+3
    const int k  = tid & 31;
    const int hb = (tid >> 5) * 4;
    #pragma unroll
    for (int j = 0; j < 4; ++j) {
        const int h  = hb + j;
        const int t0 = h * HSTEP;
        const float* wvp = wv + ((size_t)(b * L_SEQ + t0)) * 32 + k;

        float Aacc = 1.f, Bacc = 0.f;
        #pragma unroll
        for (int gq = 0; gq < 2; ++gq) {
            float wl[8], ul[8];
            #pragma unroll
            for (int e = 0; e < 8; ++e) {
                wl[e] = wvp[(gq * 8 + e) * 32];
                ul[e] = S_us[t0 + gq * 8 + e];
            }
            #pragma unroll
            for (int e = 0; e < 8; ++e) {
                float a = 1.f - ul[e];
                Aacc *= a;
                Bacc = fmaf(a, Bacc, ul[e] * wl[e]);
            }
        }
        lB[h * 32 + k] = Bacc;
        if (k == 0) lA[h] = Aacc;
    }
    __syncthreads();

    // phase B: serial chain over halves
    if (tid < 32) {
        float stv = 0.f;
        float* S0p = S0 + ((size_t)(b * 8 + r) * N_HALF) * 32 + tid;
        for (int h = 0; h < N_HALF; ++h) {
            S0p[h * 32] = stv;
            stv = fmaf(lA[h], stv, lB[h * 32 + tid]);
        }
    }
}

// ---------------------------------------------------------------------------
// Replay each 16-step half-chunk from its start state, emitting
// r_v[t][k] = sum_r rw[t][r] * s_r[k] (read BEFORE update).
// 128 blocks x 256 thr; thread = (half-unit hu, k). Loads 4-deep pipelined.
// ---------------------------------------------------------------------------
__global__ __launch_bounds__(256) void k_replay2(
    const float* __restrict__ rw, const float* __restrict__ us,
    const float* __restrict__ wv, const float* __restrict__ S0,
    float* __restrict__ rvs)
{
    const int gid = blockIdx.x * 256 + threadIdx.x;   // 0..32767
    const int k   = gid & 31;
    const int hu  = gid >> 5;        // 0..1023: b*128 + ch2
    const int b   = hu >> 7;
    const int ch2 = hu & 127;

    float s[8];
    #pragma unroll
    for (int r = 0; r < 8; ++r)
        s[r] = S0[((size_t)((b * 8 + r) * N_HALF) + ch2) * 32 + k];

    const int t0 = b * L_SEQ + ch2 * HSTEP;
    const float* rwp = rw + (size_t)t0 * 8;
    const float* usp = us + (size_t)t0 * 8;
    const float* wvp = wv + (size_t)t0 * 32 + k;
    float*       rvp = rvs + (size_t)t0 * 32 + k;

    #pragma unroll
    for (int g4 = 0; g4 < 4; ++g4) {
        float4 r0[4], r1[4], u0[4], u1[4];
        float  wl[4];
        #pragma unroll
        for (int j = 0; j < 4; ++j) {
            const int t = g4 * 4 + j;
            r0[j] = reinterpret_cast<const float4*>(rwp + t * 8)[0];
            r1[j] = reinterpret_cast<const float4*>(rwp + t * 8)[1];
            u0[j] = reinterpret_cast<const float4*>(usp + t * 8)[0];
            u1[j] = reinterpret_cast<const float4*>(usp + t * 8)[1];
            wl[j] = wvp[t * 32];
        }
        #pragma unroll
        for (int j = 0; j < 4; ++j) {
            const int t = g4 * 4 + j;
            float rv = r0[j].x*s[0] + r0[j].y*s[1] + r0[j].z*s[2] + r0[j].w*s[3]
                     + r1[j].x*s[4] + r1[j].y*s[5] + r1[j].z*s[6] + r1[j].w*s[7];
            rvp[t * 32] = rv;
            const float w = wl[j];
            s[0] = fmaf(u0[j].x, w - s[0], s[0]);
            s[1] = fmaf(u0[j].y, w - s[1], s[1]);
            s[2] = fmaf(u0[j].z, w - s[2], s[2]);
            s[3] = fmaf(u0[j].w, w - s[3], s[3]);
            s[4] = fmaf(u1[j].x, w - s[4], s[4]);
            s[5] = fmaf(u1[j].y, w - s[5], s[5]);
            s[6] = fmaf(u1[j].z, w - s[6], s[6]);
            s[7] = fmaf(u1[j].w, w - s[7], s[7]);
        }
    }
}

// ---------------------------------------------------------------------------
// out[tok, d] = mix * (sum_k rvs[tok,k] * Wrp[d,k] + brp[d]).
// v3: grid 1024 blocks x 512 thr; block = 16 tokens x all 1024 d.
// Thread owns 2 consecutive d (16 float4 weights = 64 VGPR), rv rows staged
// once in LDS (1 coalesced dword/thread), inner reads are broadcasts.
// float2 stores (8 B/lane, coalesced).
// ---------------------------------------------------------------------------
__global__ __launch_bounds__(512) void k_outproj3(
    const float* __restrict__ rvs, const float* __restrict__ Wrp,
    const float* __restrict__ brp, const float* __restrict__ mix_p,
    float* __restrict__ out)
{
    __shared__ float lrv[16 * 32];      // 2 KB

    const int tid  = threadIdx.x;
    const int d0   = tid * 2;
    const int tok0 = blockIdx.x * 16;

    // stage rv rows for this block's 16 tokens (coalesced: 512 consecutive)
    lrv[tid] = rvs[(size_t)tok0 * 32 + tid];

    float4 w0[8], w1[8];
    #pragma unroll
    for (int q = 0; q < 8; ++q) {
        w0[q] = reinterpret_cast<const float4*>(Wrp)[(size_t)d0 * 8 + q];
        w1[q] = reinterpret_cast<const float4*>(Wrp)[(size_t)(d0 + 1) * 8 + q];
    }
    const float2 bias = *reinterpret_cast<const float2*>(brp + d0);
    const float  mix  = mix_p[0];

    __syncthreads();

    #pragma unroll 4
    for (int t = 0; t < 16; ++t) {
        const float4* v4 = reinterpret_cast<const float4*>(lrv + t * 32);
        float a0 = 0.f, a1 = 0.f;
        #pragma unroll
        for (int q = 0; q < 8; ++q) {
            float4 v = v4[q];
            a0 += w0[q].x*v.x + w0[q].y*v.y + w0[q].z*v.z + w0[q].w*v.w;
            a1 += w1[q].x*v.x + w1[q].y*v.y + w1[q].z*v.z + w1[q].w*v.w;
        }
        float2 o = make_float2(mix * (a0 + bias.x), mix * (a1 + bias.y));
        *reinterpret_cast<float2*>(out + (size_t)(tok0 + t) * D_MODEL + d0) = o;
    }
}

// ---------------------------------------------------------------------------
extern "C" void kernel_launch(void* const* d_in, const int* in_sizes, int n_in,
                              void* d_out, int out_size, void* d_ws, size_t ws_size,
                              hipStream_t stream)
{
    const float* x    = (const float*)d_in[0];
    const float* ln_w = (const float*)d_in[1];
    const float* ln_b = (const float*)d_in[2];
    const float* Wrq  = (const float*)d_in[3];
    const float* brq  = (const float*)d_in[4];
    const float* Wrp  = (const float*)d_in[5];
    const float* brp  = (const float*)d_in[6];
    const float* Wwq  = (const float*)d_in[7];
    const float* bwq  = (const float*)d_in[8];
    const float* Wwv  = (const float*)d_in[9];
    const float* bwv  = (const float*)d_in[10];
    const float* Wwg  = (const float*)d_in[11];
    const float* bwg  = (const float*)d_in[12];
    const float* mix  = (const float*)d_in[13];
    float* out = (float*)d_out;

    // workspace layout (floats)
    float* ws   = (float*)d_ws;
    float* rw_b = ws;                 // 16384*8      = 131072
    float* us_b = ws + 131072;        // 16384*8      = 131072
    float* wv_b = ws + 262144;        // 16384*32     = 524288
    float* S0_b = ws + 786432;        // 8*8*128*32   = 262144
    float* rv_b = ws + 1048576;       // 16384*32     = 524288
    // Wpp/c1/c2 overlay rv_b: consumed by k_lnproj3 before k_replay2 writes rv_b
    float* Wpp  = rv_b;               // 4*1024*16 = 65536 floats
    float* c1_b = rv_b + 65536;       // 64 (52 used)
    float* c2_b = rv_b + 65600;       // 64 (52 used)
    // total: 1572864 floats = 6.0 MiB

    const size_t lds_bytes = (size_t)(2 * 4 * XQ + 64 * SSTR) * 4;  // 81152 B

    k_prep<<<52, 256, 0, stream>>>(ln_w, ln_b, Wrq, brq, Wwq, bwq,
                                   Wwv, bwv, Wwg, bwg, Wpp, c1_b, c2_b);
    k_lnproj3<<<256, 1024, lds_bytes, stream>>>(x, Wpp, c1_b, c2_b,
                                                rw_b, us_b, wv_b);
    k_scan   <<<64, 1024, 0, stream>>>(us_b, wv_b, S0_b);
    k_replay2<<<128, 256, 0, stream>>>(rw_b, us_b, wv_b, S0_b, rv_b);
    k_outproj3<<<1024, 512, 0, stream>>>(rv_b, Wrp, brp, mix, out);
}

// Round 11
// 84.223 us; speedup vs baseline: 1.9078x; 1.2243x over previous
//
#include <hip/hip_runtime.h>

#define D_MODEL 1024
#define L_SEQ   2048
#define N_BATCH 8
#define N_TOK   (N_BATCH * L_SEQ)   // 16384
#define N_REGS  8
#define D_REG   32
#define LN_EPS  1e-5f

// LDS geometry for k_lnproj3
#define KC      32                  // k-chunk size
#define XSTR    65                  // padded token stride (odd -> conflict-free)
#define XQ      (KC * XSTR)         // dwords per (buffer, quarter) = 2080
#define SSTR    57                  // epilogue tile stride (57%32=25, gcd=1)

// scan geometry: 16-step half-chunks
#define HSTEP   16
#define N_HALF  128                 // per (b,r): 2048 / 16

__device__ __forceinline__ float wred(float v) {
    #pragma unroll
    for (int off = 32; off > 0; off >>= 1) v += __shfl_xor(v, off, 64);
    return v;
}

__device__ __forceinline__ float sigmoidf(float z) {
    return 1.f / (1.f + expf(-z));
}

// ---------------------------------------------------------------------------
// Prep: fold ln_w into all 49 projection rows, pack as Wpp[g][k][16] with
// features f = g*13+i (i<13; f>=49 zero pads); c1[f] = sum_k W[f,k]*ln_w[k],
// c2[f] = sum_k W[f,k]*ln_b[k] + bias[f].
// Feature order: 0..7 = Wrq, 8..15 = Wwq, 16 = Wwg, 17..48 = Wwv.
// ---------------------------------------------------------------------------
__global__ __launch_bounds__(256) void k_prep(
    const float* __restrict__ ln_w, const float* __restrict__ ln_b,
    const float* __restrict__ Wrq,  const float* __restrict__ brq,
    const float* __restrict__ Wwq,  const float* __restrict__ bwq,
    const float* __restrict__ Wwv,  const float* __restrict__ bwv,
    const float* __restrict__ Wwg,  const float* __restrict__ bwg,
    float* __restrict__ Wpp, float* __restrict__ c1, float* __restrict__ c2)
{
    const int f = blockIdx.x;            // 0..51
    const int g = f / 13, i = f % 13;

    const float* wrow = nullptr; float bias = 0.f;
    if (f < 8)        { wrow = Wrq + f * D_MODEL;        bias = brq[f]; }
    else if (f < 16)  { wrow = Wwq + (f - 8) * D_MODEL;  bias = bwq[f - 8]; }
    else if (f == 16) { wrow = Wwg;                      bias = bwg[0]; }
    else if (f < 49)  { wrow = Wwv + (f - 17) * D_MODEL; bias = bwv[f - 17]; }

    float p1 = 0.f, p2 = 0.f;
    #pragma unroll
    for (int j = 0; j < 4; ++j) {
        const int k = j * 256 + threadIdx.x;
        float w  = wrow ? wrow[k] : 0.f;
        float wg = w * ln_w[k];
        Wpp[((size_t)(g * D_MODEL + k)) * 16 + i] = wg;
        p1 += wg;
        p2 = fmaf(w, ln_b[k], p2);
    }
    p1 = wred(p1); p2 = wred(p2);

    __shared__ float r1[4], r2[4];
    const int l = threadIdx.x & 63, w = threadIdx.x >> 6;
    if (l == 0) { r1[w] = p1; r2[w] = p2; }
    __syncthreads();
    if (threadIdx.x == 0) {
        c1[f] = r1[0] + r1[1] + r1[2] + r1[3];
        c2[f] = r2[0] + r2[1] + r2[2] + r2[3] + bias;
    }
}

// ---------------------------------------------------------------------------
// Inner projection loop over one 32-k LDS chunk. STATS: 0=none, 1=sum, 2=ss.
// Weights via wave-uniform scalar loads (s_load path — round-7 proven).
// ---------------------------------------------------------------------------
template<int STATS>
__device__ __forceinline__ void proj_chunk(
    const float* __restrict__ lx,      // LDS base: + k*XSTR + lane
    const float4* __restrict__ wr0,    // Wpp record base for this chunk
    int lane, float acc[13], float& st)
{
    #pragma unroll 4
    for (int k = 0; k < KC; ++k) {
        const float xs = lx[k * XSTR + lane];
        const float4* wr = wr0 + (k << 2);
        float4 wa = wr[0], wb = wr[1], wc = wr[2];
        float  wd = reinterpret_cast<const float*>(wr)[12];
        acc[0]  = fmaf(xs, wa.x, acc[0]);
        acc[1]  = fmaf(xs, wa.y, acc[1]);
        acc[2]  = fmaf(xs, wa.z, acc[2]);
        acc[3]  = fmaf(xs, wa.w, acc[3]);
        acc[4]  = fmaf(xs, wb.x, acc[4]);
        acc[5]  = fmaf(xs, wb.y, acc[5]);
        acc[6]  = fmaf(xs, wb.z, acc[6]);
        acc[7]  = fmaf(xs, wb.w, acc[7]);
        acc[8]  = fmaf(xs, wc.x, acc[8]);
        acc[9]  = fmaf(xs, wc.y, acc[9]);
        acc[10] = fmaf(xs, wc.z, acc[10]);
        acc[11] = fmaf(xs, wc.w, acc[11]);
        acc[12] = fmaf(xs, wd,   acc[12]);
        if (STATS == 1) st += xs;
        if (STATS == 2) st = fmaf(xs, xs, st);
    }
}

// ---------------------------------------------------------------------------
// Kernel A v3 (round-7 proven): LDS-transpose-staged x, scalar-path weights.
// Block = 1024 thr = 16 waves (4 feature-groups g x 4 K-quarters kh),
// 64 tokens per block, lane = token. Dynamic LDS: 2*4*XQ + 64*SSTR dwords.
// ---------------------------------------------------------------------------
__global__ __launch_bounds__(1024) void k_lnproj3(
    const float* __restrict__ x,
    const float* __restrict__ Wpp,
    const float* __restrict__ c1, const float* __restrict__ c2,
    float* __restrict__ rw_o, float* __restrict__ us_o, float* __restrict__ wv_o)
{
    extern __shared__ float lds[];
    float* Sb = lds + 2 * 4 * XQ;       // [64][SSTR]

    const int tid  = threadIdx.x;
    const int lane = tid & 63;
    const int wv   = tid >> 6;          // 0..15
    const int g    = wv & 3;            // feature group
    const int kh   = wv >> 2;           // K quarter
    const int tok0 = blockIdx.x * 64;

    const int gs  = __builtin_amdgcn_readfirstlane(g);
    const int khs = __builtin_amdgcn_readfirstlane(kh);

    // staging ids within the 256-thread quarter-group
    const int tq  = tid & 255;
    const int row = tq >> 3;            // 0..31 (token), +32 on pass 1
    const int c4  = tq & 7;             // float4 column (k_local = c4*4)

    const float4* x4 = reinterpret_cast<const float4*>(x);

    float4 xg[2];
    float acc[13];
    #pragma unroll
    for (int i = 0; i < 13; ++i) acc[i] = 0.f;
    float st = 0.f;

    const size_t gbase = (size_t)(tok0 + row) * 256 + khs * 64 + c4;

    // ---- prologue: stage chunk 0 ------------------------------------------
    {
        xg[0] = x4[gbase];
        xg[1] = x4[gbase + 32 * 256];
        float* dst = lds + khs * XQ + (c4 * 4) * XSTR;
        #pragma unroll
        for (int p = 0; p < 2; ++p) {
            const int r = row + 32 * p;
            dst[0 * XSTR + r] = xg[p].x;
            dst[1 * XSTR + r] = xg[p].y;
            dst[2 * XSTR + r] = xg[p].z;
            dst[3 * XSTR + r] = xg[p].w;
        }
    }
    __syncthreads();

    // ---- main loop over 8 chunks of 32 k ----------------------------------
    for (int c = 0; c < 8; ++c) {
        if (c < 7)  { // issue loads for next chunk (latency hidden by compute)
            xg[0] = x4[gbase + (size_t)(c + 1) * 8];
            xg[1] = x4[gbase + (size_t)(c + 1) * 8 + 32 * 256];
        }

        const float*  lx  = lds + ((c & 1) * 4 + khs) * XQ;
        const float4* wr0 = reinterpret_cast<const float4*>(Wpp)
                          + ((gs * D_MODEL + khs * 256 + c * KC) << 2);
        if (gs == 1)      proj_chunk<1>(lx, wr0, lane, acc, st);
        else if (gs == 2) proj_chunk<2>(lx, wr0, lane, acc, st);
        else              proj_chunk<0>(lx, wr0, lane, acc, st);

        if (c < 7) {
            float* dst = lds + (((c + 1) & 1) * 4 + khs) * XQ + (c4 * 4) * XSTR;
            #pragma unroll
            for (int p = 0; p < 2; ++p) {
                const int r = row + 32 * p;
                dst[0 * XSTR + r] = xg[p].x;
                dst[1 * XSTR + r] = xg[p].y;
                dst[2 * XSTR + r] = xg[p].z;
                dst[3 * XSTR + r] = xg[p].w;
            }
        }
        __syncthreads();
    }

    // ---- phased combine of K-quarters into Sb ------------------------------
    if (kh == 0) {
        #pragma unroll
        for (int i = 0; i < 13; ++i) Sb[lane * SSTR + g * 13 + i] = acc[i];
        if (g == 1) Sb[lane * SSTR + 52] = st;
        if (g == 2) Sb[lane * SSTR + 53] = st;
    }
    __syncthreads();
    #pragma unroll
    for (int ph = 1; ph < 4; ++ph) {
        if (kh == ph) {
            #pragma unroll
            for (int i = 0; i < 13; ++i) Sb[lane * SSTR + g * 13 + i] += acc[i];
            if (g == 1) Sb[lane * SSTR + 52] += st;
            if (g == 2) Sb[lane * SSTR + 53] += st;
        }
        __syncthreads();
    }

    // ---- epilogue: per-token softmax / sigmoid + writes --------------------
    if (tid < 256) {
        const int t  = tid & 63;
        const int q  = tid >> 6;
        const int tg = blockIdx.x * 64 + t;
        const float* St = Sb + t * SSTR;

        const float tsum = St[52], tss = St[53];
        const float mu  = tsum * (1.f / D_MODEL);
        const float var = tss * (1.f / D_MODEL) - mu * mu;
        const float rs  = rsqrtf(var + LN_EPS);

        if (q == 0) {
            float lg[8];
            #pragma unroll
            for (int r = 0; r < 8; ++r)
                lg[r] = rs * (St[r] - mu * c1[r]) + c2[r];
            float m = lg[0];
            #pragma unroll
            for (int r = 1; r < 8; ++r) m = fmaxf(m, lg[r]);
            float sm = 0.f;
            #pragma unroll
            for (int r = 0; r < 8; ++r) { lg[r] = expf(lg[r] - m); sm += lg[r]; }
            float inv = 1.f / sm;
            float4* o = reinterpret_cast<float4*>(rw_o + (size_t)tg * 8);
            o[0] = make_float4(lg[0]*inv, lg[1]*inv, lg[2]*inv, lg[3]*inv);
            o[1] = make_float4(lg[4]*inv, lg[5]*inv, lg[6]*inv, lg[7]*inv);
        } else if (q == 1) {
            float lg[8];
            #pragma unroll
            for (int r = 0; r < 8; ++r)
                lg[r] = rs * (St[8 + r] - mu * c1[8 + r]) + c2[8 + r];
            float gl = rs * (St[16] - mu * c1[16]) + c2[16];
            float m = lg[0];
            #pragma unroll
            for (int r = 1; r < 8; ++r) m = fmaxf(m, lg[r]);
            float sm = 0.f;
            #pragma unroll
            for (int r = 0; r < 8; ++r) { lg[r] = expf(lg[r] - m); sm += lg[r]; }
            float inv = sigmoidf(gl) / sm;
            float4* o = reinterpret_cast<float4*>(us_o + (size_t)tg * 8);
            o[0] = make_float4(lg[0]*inv, lg[1]*inv, lg[2]*inv, lg[3]*inv);
            o[1] = make_float4(lg[4]*inv, lg[5]*inv, lg[6]*inv, lg[7]*inv);
        } else {
            const int f0 = 17 + (q - 2) * 16;
            float4* o = reinterpret_cast<float4*>(wv_o + (size_t)tg * 32 + (q - 2) * 16);
            #pragma unroll
            for (int jq = 0; jq < 4; ++jq) {
                float v0 = rs * (St[f0 + jq*4 + 0] - mu * c1[f0 + jq*4 + 0]) + c2[f0 + jq*4 + 0];
                float v1 = rs * (St[f0 + jq*4 + 1] - mu * c1[f0 + jq*4 + 1]) + c2[f0 + jq*4 + 1];
                float v2 = rs * (St[f0 + jq*4 + 2] - mu * c1[f0 + jq*4 + 2]) + c2[f0 + jq*4 + 2];
                float v3 = rs * (St[f0 + jq*4 + 3] - mu * c1[f0 + jq*4 + 3]) + c2[f0 + jq*4 + 3];
                o[jq] = make_float4(v0, v1, v2, v3);
            }
        }
    }
}

// ---------------------------------------------------------------------------
// Fused scan (chunk-compose + chain), one block per (b,r). 64 blocks x 1024.
// ---------------------------------------------------------------------------
__global__ __launch_bounds__(1024) void k_scan(
    const float* __restrict__ us, const float* __restrict__ wv,
    float* __restrict__ S0)
{
    __shared__ float S_us[L_SEQ];           // 8 KB
    __shared__ float lA[N_HALF];            // 0.5 KB
    __shared__ float lB[N_HALF * 32];       // 16 KB

    const int tid = threadIdx.x;
    const int b   = blockIdx.x >> 3;
    const int r   = blockIdx.x & 7;

    // stage us[b, :, r]
    #pragma unroll
    for (int i = 0; i < 2; ++i) {
        const int t = i * 1024 + tid;
        S_us[t] = us[((size_t)(b * L_SEQ + t)) * 8 + r];
    }
    __syncthreads();

    // phase A: thread -> k = tid&31, halves hb..hb+3
    const int k  = tid & 31;
    const int hb = (tid >> 5) * 4;
    #pragma unroll
    for (int j = 0; j < 4; ++j) {
        const int h  = hb + j;
        const int t0 = h * HSTEP;
        const float* wvp = wv + ((size_t)(b * L_SEQ + t0)) * 32 + k;

        float Aacc = 1.f, Bacc = 0.f;
        #pragma unroll
        for (int gq = 0; gq < 2; ++gq) {
            float wl[8], ul[8];
            #pragma unroll
            for (int e = 0; e < 8; ++e) {
                wl[e] = wvp[(gq * 8 + e) * 32];
                ul[e] = S_us[t0 + gq * 8 + e];
            }
            #pragma unroll
            for (int e = 0; e < 8; ++e) {
                float a = 1.f - ul[e];
                Aacc *= a;
                Bacc = fmaf(a, Bacc, ul[e] * wl[e]);
            }
        }
        lB[h * 32 + k] = Bacc;
        if (k == 0) lA[h] = Aacc;
    }
    __syncthreads();

    // phase B: serial chain over halves
    if (tid < 32) {
        float stv = 0.f;
        float* S0p = S0 + ((size_t)(b * 8 + r) * N_HALF) * 32 + tid;
        for (int h = 0; h < N_HALF; ++h) {
            S0p[h * 32] = stv;
            stv = fmaf(lA[h], stv, lB[h * 32 + tid]);
        }
    }
}

// ---------------------------------------------------------------------------
// Replay each 16-step half-chunk from its start state, emitting
// r_v[t][k] = sum_r rw[t][r] * s_r[k] (read BEFORE update).
// 128 blocks x 256 thr; thread = (half-unit hu, k). Loads 4-deep pipelined.
// ---------------------------------------------------------------------------
__global__ __launch_bounds__(256) void k_replay2(
    const float* __restrict__ rw, const float* __restrict__ us,
    const float* __restrict__ wv, const float* __restrict__ S0,
    float* __restrict__ rvs)
{
    const int gid = blockIdx.x * 256 + threadIdx.x;   // 0..32767
    const int k   = gid & 31;
    const int hu  = gid >> 5;        // 0..1023: b*128 + ch2
    const int b   = hu >> 7;
    const int ch2 = hu & 127;

    float s[8];
    #pragma unroll
    for (int r = 0; r < 8; ++r)
        s[r] = S0[((size_t)((b * 8 + r) * N_HALF) + ch2) * 32 + k];

    const int t0 = b * L_SEQ + ch2 * HSTEP;
    const float* rwp = rw + (size_t)t0 * 8;
    const float* usp = us + (size_t)t0 * 8;
    const float* wvp = wv + (size_t)t0 * 32 + k;
    float*       rvp = rvs + (size_t)t0 * 32 + k;

    #pragma unroll
    for (int g4 = 0; g4 < 4; ++g4) {
        float4 r0[4], r1[4], u0[4], u1[4];
        float  wl[4];
        #pragma unroll
        for (int j = 0; j < 4; ++j) {
            const int t = g4 * 4 + j;
            r0[j] = reinterpret_cast<const float4*>(rwp + t * 8)[0];
            r1[j] = reinterpret_cast<const float4*>(rwp + t * 8)[1];
            u0[j] = reinterpret_cast<const float4*>(usp + t * 8)[0];
            u1[j] = reinterpret_cast<const float4*>(usp + t * 8)[1];
            wl[j] = wvp[t * 32];
        }
        #pragma unroll
        for (int j = 0; j < 4; ++j) {
            const int t = g4 * 4 + j;
            float rv = r0[j].x*s[0] + r0[j].y*s[1] + r0[j].z*s[2] + r0[j].w*s[3]
                     + r1[j].x*s[4] + r1[j].y*s[5] + r1[j].z*s[6] + r1[j].w*s[7];
            rvp[t * 32] = rv;
            const float w = wl[j];
            s[0] = fmaf(u0[j].x, w - s[0], s[0]);
            s[1] = fmaf(u0[j].y, w - s[1], s[1]);
            s[2] = fmaf(u0[j].z, w - s[2], s[2]);
            s[3] = fmaf(u0[j].w, w - s[3], s[3]);
            s[4] = fmaf(u1[j].x, w - s[4], s[4]);
            s[5] = fmaf(u1[j].y, w - s[5], s[5]);
            s[6] = fmaf(u1[j].z, w - s[6], s[6]);
            s[7] = fmaf(u1[j].w, w - s[7], s[7]);
        }
    }
}

// ---------------------------------------------------------------------------
// out[b,t,d] = mix * (sum_k rvs[b,t,k] * Wrp[d,k] + brp[d]).
// v1 (rounds 1-7, measured-fast): thread owns one d (Wrp row in 32 regs),
// loops 64 tokens, scalar dword stores. Grid (256 token-tiles, 4 d-tiles).
// ---------------------------------------------------------------------------
__global__ __launch_bounds__(256) void k_outproj(
    const float* __restrict__ rvs, const float* __restrict__ Wrp,
    const float* __restrict__ brp, const float* __restrict__ mix_p,
    float* __restrict__ out)
{
    const int d    = blockIdx.y * 256 + threadIdx.x;
    const int tok0 = blockIdx.x * 64;

    float4 wr[8];
    #pragma unroll
    for (int q = 0; q < 8; ++q)
        wr[q] = reinterpret_cast<const float4*>(Wrp)[(size_t)d * 8 + q];

    const float bias = brp[d];
    const float mix  = mix_p[0];

    for (int t = 0; t < 64; ++t) {
        const float4* rv = reinterpret_cast<const float4*>(rvs + (size_t)(tok0 + t) * 32);
        float acc = 0.f;
        #pragma unroll
        for (int q = 0; q < 8; ++q) {
            float4 v = rv[q];
            acc += wr[q].x*v.x + wr[q].y*v.y + wr[q].z*v.z + wr[q].w*v.w;
        }
        out[(size_t)(tok0 + t) * D_MODEL + d] = mix * (acc + bias);
    }
}

// ---------------------------------------------------------------------------
extern "C" void kernel_launch(void* const* d_in, const int* in_sizes, int n_in,
                              void* d_out, int out_size, void* d_ws, size_t ws_size,
                              hipStream_t stream)
{
    const float* x    = (const float*)d_in[0];
    const float* ln_w = (const float*)d_in[1];
    const float* ln_b = (const float*)d_in[2];
    const float* Wrq  = (const float*)d_in[3];
    const float* brq  = (const float*)d_in[4];
    const float* Wrp  = (const float*)d_in[5];
    const float* brp  = (const float*)d_in[6];
    const float* Wwq  = (const float*)d_in[7];
    const float* bwq  = (const float*)d_in[8];
    const float* Wwv  = (const float*)d_in[9];
    const float* bwv  = (const float*)d_in[10];
    const float* Wwg  = (const float*)d_in[11];
    const float* bwg  = (const float*)d_in[12];
    const float* mix  = (const float*)d_in[13];
    float* out = (float*)d_out;

    // workspace layout (floats)
    float* ws   = (float*)d_ws;
    float* rw_b = ws;                 // 16384*8      = 131072
    float* us_b = ws + 131072;        // 16384*8      = 131072
    float* wv_b = ws + 262144;        // 16384*32     = 524288
    float* S0_b = ws + 786432;        // 8*8*128*32   = 262144
    float* rv_b = ws + 1048576;       // 16384*32     = 524288
    // Wpp/c1/c2 overlay rv_b: consumed by k_lnproj3 before k_replay2 writes rv_b
    float* Wpp  = rv_b;               // 4*1024*16 = 65536 floats
    float* c1_b = rv_b + 65536;       // 64 (52 used)
    float* c2_b = rv_b + 65600;       // 64 (52 used)
    // total: 1572864 floats = 6.0 MiB

    const size_t lds_bytes = (size_t)(2 * 4 * XQ + 64 * SSTR) * 4;  // 81152 B

    k_prep<<<52, 256, 0, stream>>>(ln_w, ln_b, Wrq, brq, Wwq, bwq,
                                   Wwv, bwv, Wwg, bwg, Wpp, c1_b, c2_b);
    k_lnproj3<<<256, 1024, lds_bytes, stream>>>(x, Wpp, c1_b, c2_b,
                                                rw_b, us_b, wv_b);
    k_scan   <<<64, 1024, 0, stream>>>(us_b, wv_b, S0_b);
    k_replay2<<<128, 256, 0, stream>>>(rw_b, us_b, wv_b, S0_b, rv_b);
    dim3 gc(N_TOK / 64, 4);
    k_outproj<<<gc, 256, 0, stream>>>(rv_b, Wrp, brp, mix, out);
}